// Round 1
// baseline (79.496 us; speedup 1.0000x reference)
//
#include <hip/hip_runtime.h>
#include <hip/hip_bf16.h>
#include <stdint.h>

#define MDIM 16384
#define NDIM 1024
#define KDIM 1024

typedef __bf16 bf16x8 __attribute__((ext_vector_type(8)));
typedef float f32x4 __attribute__((ext_vector_type(4)));

#define GLOBAL_CPTR(p) ((const __attribute__((address_space(1))) void*)(p))
#define LDS_PTR(p)     ((__attribute__((address_space(3))) void*)(p))

// ---------------- fp32 -> bf16 (RNE) convert, 8 elems/thread ----------------
__device__ inline ushort f2bf_rne(float f) {
    union { float f; uint32_t u; } c; c.f = f;
    uint32_t u = c.u;
    return (ushort)((u + 0x7fffu + ((u >> 16) & 1u)) >> 16);
}

__global__ __launch_bounds__(256) void cvt_f32_bf16(const float* __restrict__ src,
                                                    ushort* __restrict__ dst, int n8) {
    int i = blockIdx.x * 256 + threadIdx.x;
    if (i >= n8) return;
    const float4* s4 = (const float4*)src;
    float4 a = s4[2 * i];
    float4 b = s4[2 * i + 1];
    union { ushort us[8]; uint4 u4; } p;
    p.us[0] = f2bf_rne(a.x); p.us[1] = f2bf_rne(a.y);
    p.us[2] = f2bf_rne(a.z); p.us[3] = f2bf_rne(a.w);
    p.us[4] = f2bf_rne(b.x); p.us[5] = f2bf_rne(b.y);
    p.us[6] = f2bf_rne(b.z); p.us[7] = f2bf_rne(b.w);
    ((uint4*)dst)[i] = p.u4;
}

// ---------------- bf16 GEMM: C = A(MxK) * B^T (B is NxK row-major) + bias ---
// m97 structure: 128x128 tile, BK=32, 4 waves (2x2), 16x16x32 MFMA, 4x4 acc.
__global__ __launch_bounds__(256) void gemm_bf16_bt(const ushort* __restrict__ A,
                                                    const ushort* __restrict__ B,
                                                    const float* __restrict__ bias,
                                                    float* __restrict__ C) {
    __shared__ ushort As[128 * 32];   // [row][k] linear, 8 KiB
    __shared__ ushort Bs[128 * 32];   // [row(n)][k] linear, 8 KiB

    const int tid  = threadIdx.x;
    const int lane = tid & 63;
    const int wave = tid >> 6;
    const int wr   = wave >> 1;       // 0..1  (M half)
    const int wc   = wave & 1;        // 0..1  (N half)
    const int l15  = lane & 15;
    const int l4   = lane >> 4;

    const int brow = blockIdx.y * 128;
    const int bcol = blockIdx.x * 128;

    // staging sources: thread t covers tile elems [t*8, t*8+8) of a 64-row half
    // row = t/4 (+64 for issue 1), col = (t&3)*8
    const ushort* Ag = A + (size_t)(brow + (tid >> 2)) * KDIM + (tid & 3) * 8;
    const ushort* Bg = B + (size_t)(bcol + (tid >> 2)) * KDIM + (tid & 3) * 8;

    // LDS staging destinations (HW: wave-uniform base + lane*16B; per-thread
    // pointer's first-lane value is exactly the wave base)
    ushort* AsD = As + tid * 8;
    ushort* BsD = Bs + tid * 8;

    // LDS fragment read bases: lane l reads row (sub16 + l15), k = l4*8, 16B
    const ushort* ArdBase = As + (wr * 64 + l15) * 32 + l4 * 8;
    const ushort* BrdBase = Bs + (wc * 64 + l15) * 32 + l4 * 8;

    f32x4 acc[4][4] = {};

    for (int kt = 0; kt < KDIM / 32; ++kt) {
        __builtin_amdgcn_global_load_lds(GLOBAL_CPTR(Ag),            LDS_PTR(AsD),        16, 0, 0);
        __builtin_amdgcn_global_load_lds(GLOBAL_CPTR(Ag + 64*KDIM),  LDS_PTR(AsD + 2048), 16, 0, 0);
        __builtin_amdgcn_global_load_lds(GLOBAL_CPTR(Bg),            LDS_PTR(BsD),        16, 0, 0);
        __builtin_amdgcn_global_load_lds(GLOBAL_CPTR(Bg + 64*KDIM),  LDS_PTR(BsD + 2048), 16, 0, 0);
        Ag += 32; Bg += 32;
        __syncthreads();   // vmcnt(0) drain + barrier: staged tile visible

        bf16x8 af[4], bfr[4];
#pragma unroll
        for (int m = 0; m < 4; ++m)
            af[m] = *(const bf16x8*)(ArdBase + m * 16 * 32);
#pragma unroll
        for (int n = 0; n < 4; ++n)
            bfr[n] = *(const bf16x8*)(BrdBase + n * 16 * 32);

#pragma unroll
        for (int m = 0; m < 4; ++m)
#pragma unroll
            for (int n = 0; n < 4; ++n)
                acc[m][n] = __builtin_amdgcn_mfma_f32_16x16x32_bf16(af[m], bfr[n], acc[m][n], 0, 0, 0);

        __syncthreads();   // protect LDS before next stage overwrites
    }

    // epilogue: C[row][col] = acc + bias[col]
    float bv[4];
#pragma unroll
    for (int n = 0; n < 4; ++n)
        bv[n] = bias[bcol + wc * 64 + n * 16 + l15];

#pragma unroll
    for (int m = 0; m < 4; ++m) {
        const int row0 = brow + wr * 64 + m * 16 + l4 * 4;
#pragma unroll
        for (int n = 0; n < 4; ++n) {
            const int col = bcol + wc * 64 + n * 16 + l15;
#pragma unroll
            for (int i = 0; i < 4; ++i)
                C[(size_t)(row0 + i) * NDIM + col] = acc[m][n][i] + bv[n];
        }
    }
}

// ---------------- naive fp32 fallback (only if ws too small) ----------------
__global__ __launch_bounds__(256) void gemm_naive(const float* __restrict__ x,
                                                  const float* __restrict__ w,
                                                  const float* __restrict__ bias,
                                                  float* __restrict__ out) {
    long o = (long)blockIdx.x * 256 + threadIdx.x;
    if (o >= (long)MDIM * NDIM) return;
    int b = (int)(o / NDIM), n = (int)(o % NDIM);
    const float* xr = x + (long)b * KDIM;
    const float* wr = w + (long)n * KDIM;
    float s = 0.f;
    for (int k = 0; k < KDIM; ++k) s += xr[k] * wr[k];
    out[o] = s + bias[n];
}

extern "C" void kernel_launch(void* const* d_in, const int* in_sizes, int n_in,
                              void* d_out, int out_size, void* d_ws, size_t ws_size,
                              hipStream_t stream) {
    const float* x    = (const float*)d_in[0];
    const float* w    = (const float*)d_in[1];
    const float* bias = (const float*)d_in[2];
    float* out = (float*)d_out;

    const size_t need = ((size_t)MDIM * KDIM + (size_t)NDIM * KDIM) * sizeof(ushort);
    if (ws_size >= need) {
        ushort* xb = (ushort*)d_ws;
        ushort* wb = xb + (size_t)MDIM * KDIM;
        const int n8x = MDIM * KDIM / 8;   // 2,097,152
        const int n8w = NDIM * KDIM / 8;   //   131,072
        cvt_f32_bf16<<<n8x / 256, 256, 0, stream>>>(x, xb, n8x);
        cvt_f32_bf16<<<n8w / 256, 256, 0, stream>>>(w, wb, n8w);
        dim3 grid(NDIM / 128, MDIM / 128);   // (8, 128) = 1024 blocks
        gemm_bf16_bt<<<grid, 256, 0, stream>>>(xb, wb, bias, out);
    } else {
        const long total = (long)MDIM * NDIM;
        gemm_naive<<<(int)((total + 255) / 256), 256, 0, stream>>>(x, w, bias, out);
    }
}

// Round 2
// 70.352 us; speedup vs baseline: 1.1300x; 1.1300x over previous
//
#include <hip/hip_runtime.h>
#include <hip/hip_bf16.h>
#include <stdint.h>

#define MDIM 16384
#define NDIM 1024
#define KDIM 1024
#define BM 256
#define BN 256
#define BK 64
#define NT (KDIM / BK)   // 16 K-tiles

typedef __bf16 bf16x8 __attribute__((ext_vector_type(8)));
typedef float f32x4 __attribute__((ext_vector_type(4)));

#define GLOBAL_CPTR(p) ((const __attribute__((address_space(1))) void*)(p))
#define LDS_PTR(p)     ((__attribute__((address_space(3))) void*)(p))

// ---------------- fp32 -> bf16 (RNE) convert, 8 elems/thread ----------------
__device__ inline ushort f2bf_rne(float f) {
    union { float f; uint32_t u; } c; c.f = f;
    uint32_t u = c.u;
    return (ushort)((u + 0x7fffu + ((u >> 16) & 1u)) >> 16);
}

__global__ __launch_bounds__(256) void cvt_f32_bf16(const float* __restrict__ src,
                                                    ushort* __restrict__ dst, int n8) {
    int i = blockIdx.x * 256 + threadIdx.x;
    if (i >= n8) return;
    const float4* s4 = (const float4*)src;
    float4 a = s4[2 * i];
    float4 b = s4[2 * i + 1];
    union { ushort us[8]; uint4 u4; } p;
    p.us[0] = f2bf_rne(a.x); p.us[1] = f2bf_rne(a.y);
    p.us[2] = f2bf_rne(a.z); p.us[3] = f2bf_rne(a.w);
    p.us[4] = f2bf_rne(b.x); p.us[5] = f2bf_rne(b.y);
    p.us[6] = f2bf_rne(b.z); p.us[7] = f2bf_rne(b.w);
    ((uint4*)dst)[i] = p.u4;
}

// ---------------- 256x256 8-phase bf16 GEMM (T2+T3+T4+T5) -------------------
// C = A(MxK) * B^T (B is NxK row-major) + bias.  8 waves (2M x 4N), BK=64.
// LDS: 2 dbuf x (A 256x64 + B 256x64) bf16 = 128 KiB, XOR-swizzled
// (byte ^= (row&7)<<4) via pre-swizzled global source + swizzled ds_read.
__global__ __launch_bounds__(512, 2) void gemm_8ph(const ushort* __restrict__ A,
                                                   const ushort* __restrict__ B,
                                                   const float* __restrict__ bias,
                                                   float* __restrict__ C) {
    __shared__ ushort As[2][BM * BK];   // 2 x 32 KiB
    __shared__ ushort Bs[2][BN * BK];   // 2 x 32 KiB

    const int tid  = threadIdx.x;
    const int lane = tid & 63;
    const int wave = tid >> 6;
    const int wr   = wave >> 2;   // 0..1 : M half (128 rows)
    const int wc   = wave & 3;    // 0..3 : N quarter (64 cols)
    const int l15  = lane & 15;
    const int l4   = lane >> 4;

    const int brow = blockIdx.y * BM;
    const int bcol = blockIdx.x * BN;

    // ---- staging: thread t covers one 16B chunk per issue; linear LDS dest,
    // inverse-swizzled global source (rule 21; XOR is an involution).
    const int lr = tid >> 3;                                   // local row 0..63
    const int kc = (((tid & 7) * 16) ^ ((lr & 7) << 4)) >> 1;  // swizzled ushort col
    const ushort* Asrc = A + (size_t)(brow + lr) * KDIM + kc;
    const ushort* Bsrc = B + (size_t)(bcol + lr) * KDIM + kc;

    // ---- fragment ds_read byte offsets (swizzled), kk = 0/1 halves of BK=64
    const int sw   = (l15 & 7) << 4;
    const int off0 = l15 * 128 + ((l4 * 16) ^ sw);
    const int off1 = l15 * 128 + (((l4 * 16) + 64) ^ sw);

#define STG_A(bb, t_, r0) __builtin_amdgcn_global_load_lds( \
        GLOBAL_CPTR(Asrc + (size_t)(r0) * KDIM + (t_) * BK), \
        LDS_PTR(&As[bb][(r0) * BK + tid * 8]), 16, 0, 0)
#define STG_B(bb, t_, r0) __builtin_amdgcn_global_load_lds( \
        GLOBAL_CPTR(Bsrc + (size_t)(r0) * KDIM + (t_) * BK), \
        LDS_PTR(&Bs[bb][(r0) * BK + tid * 8]), 16, 0, 0)

#define LOAD_A(bb, mh) do { _Pragma("unroll") \
    for (int i_ = 0; i_ < 4; ++i_) { \
        const char* pb_ = (const char*)&As[bb][0] + (wr * 128 + (mh) * 64 + i_ * 16) * 128; \
        af[i_][0] = *(const bf16x8*)(pb_ + off0); \
        af[i_][1] = *(const bf16x8*)(pb_ + off1); } } while (0)

#define LOAD_B(bb, nh) do { _Pragma("unroll") \
    for (int j_ = 0; j_ < 2; ++j_) { \
        const char* pb_ = (const char*)&Bs[bb][0] + (wc * 64 + (nh) * 32 + j_ * 16) * 128; \
        bfr[nh][j_][0] = *(const bf16x8*)(pb_ + off0); \
        bfr[nh][j_][1] = *(const bf16x8*)(pb_ + off1); } } while (0)

#define MFMA_Q(mh, nh) do { __builtin_amdgcn_s_setprio(1); _Pragma("unroll") \
    for (int i_ = 0; i_ < 4; ++i_) { _Pragma("unroll") \
        for (int j_ = 0; j_ < 2; ++j_) { \
            acc[(mh)*4 + i_][(nh)*2 + j_] = __builtin_amdgcn_mfma_f32_16x16x32_bf16( \
                af[i_][0], bfr[nh][j_][0], acc[(mh)*4 + i_][(nh)*2 + j_], 0, 0, 0); \
            acc[(mh)*4 + i_][(nh)*2 + j_] = __builtin_amdgcn_mfma_f32_16x16x32_bf16( \
                af[i_][1], bfr[nh][j_][1], acc[(mh)*4 + i_][(nh)*2 + j_], 0, 0, 0); } } \
    __builtin_amdgcn_s_setprio(0); } while (0)

#define BARRIER __builtin_amdgcn_s_barrier()
#define LGKM0 asm volatile("s_waitcnt lgkmcnt(0)" ::: "memory")

    bf16x8 af[4][2];        // current m-half A frags
    bf16x8 bfr[2][2][2];    // both n-half B frags [nh][j][kk]
    f32x4 acc[8][4] = {};   // [mh*4+i][nh*2+j]

    // ---- prologue: tile0 full (buf0) + tile1 A-halves (buf1); wait tile0.
    STG_A(0, 0, 0); STG_A(0, 0, 64); STG_A(0, 0, 128); STG_A(0, 0, 192);
    STG_B(0, 0, 0); STG_B(0, 0, 64); STG_B(0, 0, 128); STG_B(0, 0, 192);
    STG_A(1, 1, 0); STG_A(1, 1, 64); STG_A(1, 1, 128); STG_A(1, 1, 192);
    asm volatile("s_waitcnt vmcnt(4)" ::: "memory");
    BARRIER;

    // Per K-tile t (buf b=t&1): 4 phases; issue t+1's B during ph1/ph2 (buf b^1),
    // t+2's A during ph4 (buf b — safe: all reads of buf b retired behind ph3's
    // barrier); counted vmcnt(4) once per tile guarantees tile t+1 fully staged.
#define TILE(bb, t_) do { \
    /* ph1: quadrant (m0,n0) */ \
    LOAD_A(bb, 0); \
    LOAD_B(bb, 0); \
    if ((t_) + 1 < NT) { STG_B((bb) ^ 1, (t_) + 1, 0); STG_B((bb) ^ 1, (t_) + 1, 64); } \
    BARRIER; LGKM0; MFMA_Q(0, 0); BARRIER; \
    /* ph2: quadrant (m0,n1) */ \
    LOAD_B(bb, 1); \
    if ((t_) + 1 < NT) { STG_B((bb) ^ 1, (t_) + 1, 128); STG_B((bb) ^ 1, (t_) + 1, 192); } \
    BARRIER; LGKM0; MFMA_Q(0, 1); BARRIER; \
    /* ph3: quadrant (m1,n0) */ \
    LOAD_A(bb, 1); \
    BARRIER; LGKM0; MFMA_Q(1, 0); BARRIER; \
    /* ph4: quadrant (m1,n1); prefetch t+2 A; counted wait */ \
    if ((t_) + 2 < NT) { \
        STG_A(bb, (t_) + 2, 0); STG_A(bb, (t_) + 2, 64); \
        STG_A(bb, (t_) + 2, 128); STG_A(bb, (t_) + 2, 192); \
        asm volatile("s_waitcnt vmcnt(4)" ::: "memory"); \
    } else if ((t_) + 1 < NT) { \
        asm volatile("s_waitcnt vmcnt(0)" ::: "memory"); \
    } \
    BARRIER; MFMA_Q(1, 1); BARRIER; \
} while (0)

#pragma unroll 1
    for (int t = 0; t < NT; t += 2) {
        TILE(0, t);
        TILE(1, t + 1);
    }

    // ---- epilogue: C = acc + bias (verified m97 C/D mapping)
#pragma unroll
    for (int mh = 0; mh < 2; ++mh)
#pragma unroll
        for (int i = 0; i < 4; ++i)
#pragma unroll
            for (int nh = 0; nh < 2; ++nh)
#pragma unroll
                for (int j = 0; j < 2; ++j) {
                    f32x4 v = acc[mh * 4 + i][nh * 2 + j];
                    const int row0 = brow + wr * 128 + mh * 64 + i * 16 + l4 * 4;
                    const int col  = bcol + wc * 64 + nh * 32 + j * 16 + l15;
                    const float bb = bias[col];
#pragma unroll
                    for (int r = 0; r < 4; ++r)
                        C[(size_t)(row0 + r) * NDIM + col] = v[r] + bb;
                }
}

// ---------------- naive fp32 fallback (only if ws too small) ----------------
__global__ __launch_bounds__(256) void gemm_naive(const float* __restrict__ x,
                                                  const float* __restrict__ w,
                                                  const float* __restrict__ bias,
                                                  float* __restrict__ out) {
    long o = (long)blockIdx.x * 256 + threadIdx.x;
    if (o >= (long)MDIM * NDIM) return;
    int b = (int)(o / NDIM), n = (int)(o % NDIM);
    const float* xr = x + (long)b * KDIM;
    const float* wr = w + (long)n * KDIM;
    float s = 0.f;
    for (int k = 0; k < KDIM; ++k) s += xr[k] * wr[k];
    out[o] = s + bias[n];
}

extern "C" void kernel_launch(void* const* d_in, const int* in_sizes, int n_in,
                              void* d_out, int out_size, void* d_ws, size_t ws_size,
                              hipStream_t stream) {
    const float* x    = (const float*)d_in[0];
    const float* w    = (const float*)d_in[1];
    const float* bias = (const float*)d_in[2];
    float* out = (float*)d_out;

    const size_t need = ((size_t)MDIM * KDIM + (size_t)NDIM * KDIM) * sizeof(ushort);
    if (ws_size >= need) {
        ushort* xb = (ushort*)d_ws;
        ushort* wb = xb + (size_t)MDIM * KDIM;
        const int n8x = MDIM * KDIM / 8;   // 2,097,152
        const int n8w = NDIM * KDIM / 8;   //   131,072
        cvt_f32_bf16<<<n8x / 256, 256, 0, stream>>>(x, xb, n8x);
        cvt_f32_bf16<<<n8w / 256, 256, 0, stream>>>(w, wb, n8w);
        dim3 grid(NDIM / BN, MDIM / BM);   // (4, 64) = 256 blocks
        gemm_8ph<<<grid, 512, 0, stream>>>(xb, wb, bias, out);
    } else {
        const long total = (long)MDIM * NDIM;
        gemm_naive<<<(int)((total + 255) / 256), 256, 0, stream>>>(x, w, bias, out);
    }
}

// Round 3
// 60.668 us; speedup vs baseline: 1.3103x; 1.1596x over previous
//
#include <hip/hip_runtime.h>
#include <hip/hip_bf16.h>
#include <stdint.h>

#define MDIM 16384
#define NDIM 1024
#define KDIM 1024
#define BM 256
#define BN 256
#define BK 64
#define NT (KDIM / BK)   // 16 K-tiles

typedef __bf16 bf16x8 __attribute__((ext_vector_type(8)));
typedef float f32x4 __attribute__((ext_vector_type(4)));
typedef uint  u32x4 __attribute__((ext_vector_type(4)));

#define GLOBAL_CPTR(p) ((const __attribute__((address_space(1))) void*)(p))
#define LDS_PTR(p)     ((__attribute__((address_space(3))) void*)(p))

// ---------------- fp32 -> bf16 (RNE) convert (used for W only) --------------
__device__ inline ushort f2bf_rne(float f) {
    union { float f; uint32_t u; } c; c.f = f;
    uint32_t u = c.u;
    return (ushort)((u + 0x7fffu + ((u >> 16) & 1u)) >> 16);
}

__global__ __launch_bounds__(256) void cvt_f32_bf16(const float* __restrict__ src,
                                                    ushort* __restrict__ dst, int n8) {
    int i = blockIdx.x * 256 + threadIdx.x;
    if (i >= n8) return;
    const float4* s4 = (const float4*)src;
    float4 a = s4[2 * i];
    float4 b = s4[2 * i + 1];
    union { ushort us[8]; uint4 u4; } p;
    p.us[0] = f2bf_rne(a.x); p.us[1] = f2bf_rne(a.y);
    p.us[2] = f2bf_rne(a.z); p.us[3] = f2bf_rne(a.w);
    p.us[4] = f2bf_rne(b.x); p.us[5] = f2bf_rne(b.y);
    p.us[6] = f2bf_rne(b.z); p.us[7] = f2bf_rne(b.w);
    ((uint4*)dst)[i] = p.u4;
}

__device__ inline uint pk2bf(float lo, float hi) {
    union { __hip_bfloat162 h2; uint u; } c;
    c.h2 = __float22bfloat162_rn(float2{lo, hi});
    return c.u;
}

// ---------------- fused 256x256 8-phase GEMM ---------------------------------
// C = A(MxK, fp32!) * B^T (B = W bf16, NxK) + bias.  A is converted fp32->bf16
// in-kernel during reg-staging (T14), written to XOR-swizzled LDS.
__global__ __launch_bounds__(512, 2) void gemm_8ph(const float* __restrict__ A,
                                                   const ushort* __restrict__ B,
                                                   const float* __restrict__ bias,
                                                   float* __restrict__ C) {
    __shared__ ushort As[2][BM * BK];   // 2 x 32 KiB
    __shared__ ushort Bs[2][BN * BK];   // 2 x 32 KiB

    const int tid  = threadIdx.x;
    const int lane = tid & 63;
    const int wave = tid >> 6;
    const int wr   = wave >> 2;   // 0..1 : M half
    const int wc   = wave & 3;    // 0..3 : N quarter
    const int l15  = lane & 15;
    const int l4   = lane >> 4;

    // T1: chunked XCD swizzle (bijective, 256 % 8 == 0). Consecutive hw blocks
    // round-robin XCDs; give each XCD 8 contiguous brow-groups x all 4 bcols
    // so the 4 blocks sharing an A-panel hit the same L2.
    const int lin  = blockIdx.y * gridDim.x + blockIdx.x;   // 0..255
    const int swz  = (lin & 7) * 32 + (lin >> 3);
    const int brow = (swz >> 2) * BM;
    const int bcol = (swz & 3) * BN;

    const int lrow = tid >> 3;           // 0..63
    const int lcb  = (tid & 7) * 16;     // byte col within row (pre-swizzle)
    const int swb  = (lrow & 7) << 4;
    const int wb0  = lrow * 128 + (lcb ^ swb);   // swizzled ds_write byte off

    // A global source: fp32, LINEAR (swizzle applied at ds_write)
    const float*  Ag   = A + (size_t)(brow + lrow) * KDIM + (tid & 7) * 8;
    // B global source: bf16, inverse-swizzled col (global_load_lds is linear)
    const ushort* Bsrc = B + (size_t)(bcol + lrow) * KDIM + ((lcb ^ swb) >> 1);

    // fragment ds_read byte offsets (swizzled)
    const int sw   = (l15 & 7) << 4;
    const int off0 = l15 * 128 + ((l4 * 16) ^ sw);
    const int off1 = l15 * 128 + (((l4 * 16) + 64) ^ sw);

#define BARRIER __builtin_amdgcn_s_barrier()
#define LGKM0  asm volatile("s_waitcnt lgkmcnt(0)" ::: "memory")
#define VM0    asm volatile("s_waitcnt vmcnt(0)" ::: "memory")
#define SCHED0 __builtin_amdgcn_sched_barrier(0)
#define GLD4(d, p) asm volatile("global_load_dwordx4 %0, %1, off" : "=v"(d) : "v"(p) : "memory")

#define STG_B(bb, t_, r0) __builtin_amdgcn_global_load_lds( \
        GLOBAL_CPTR(Bsrc + (size_t)(r0) * KDIM + (t_) * BK), \
        LDS_PTR(&Bs[bb][(r0) * BK + tid * 8]), 16, 0, 0)

    // load one A half-tile (rows rbase..rbase+128) for K-tile t_ into sr[4]
#define GLDA_H(sr, t_, rbase) do { \
    const float* p0_ = Ag + (size_t)(rbase) * KDIM + (t_) * BK; \
    const float* p1_ = Ag + (size_t)((rbase) + 64) * KDIM + (t_) * BK; \
    GLD4(sr[0], p0_); GLD4(sr[1], p0_ + 4); \
    GLD4(sr[2], p1_); GLD4(sr[3], p1_ + 4); } while (0)

    // convert + swizzled ds_write of one A half-tile
#define CVTW_H(sr, bb, rbase) do { \
    u32x4 k0_, k1_; \
    k0_.x = pk2bf(sr[0].x, sr[0].y); k0_.y = pk2bf(sr[0].z, sr[0].w); \
    k0_.z = pk2bf(sr[1].x, sr[1].y); k0_.w = pk2bf(sr[1].z, sr[1].w); \
    k1_.x = pk2bf(sr[2].x, sr[2].y); k1_.y = pk2bf(sr[2].z, sr[2].w); \
    k1_.z = pk2bf(sr[3].x, sr[3].y); k1_.w = pk2bf(sr[3].z, sr[3].w); \
    *(u32x4*)((char*)&As[bb][0] + (rbase) * 128 + wb0) = k0_; \
    *(u32x4*)((char*)&As[bb][0] + ((rbase) + 64) * 128 + wb0) = k1_; } while (0)

#define LOAD_A(bb, mh) do { _Pragma("unroll") \
    for (int i_ = 0; i_ < 4; ++i_) { \
        const char* pb_ = (const char*)&As[bb][0] + (wr * 128 + (mh) * 64 + i_ * 16) * 128; \
        af[i_][0] = *(const bf16x8*)(pb_ + off0); \
        af[i_][1] = *(const bf16x8*)(pb_ + off1); } } while (0)

#define LOAD_B(bb, nh) do { _Pragma("unroll") \
    for (int j_ = 0; j_ < 2; ++j_) { \
        const char* pb_ = (const char*)&Bs[bb][0] + (wc * 64 + (nh) * 32 + j_ * 16) * 128; \
        bfr[j_][0] = *(const bf16x8*)(pb_ + off0); \
        bfr[j_][1] = *(const bf16x8*)(pb_ + off1); } } while (0)

#define MFMA_Q(mh, nh) do { __builtin_amdgcn_s_setprio(1); _Pragma("unroll") \
    for (int i_ = 0; i_ < 4; ++i_) { _Pragma("unroll") \
        for (int j_ = 0; j_ < 2; ++j_) { \
            acc[(mh)*4 + i_][(nh)*2 + j_] = __builtin_amdgcn_mfma_f32_16x16x32_bf16( \
                af[i_][0], bfr[j_][0], acc[(mh)*4 + i_][(nh)*2 + j_], 0, 0, 0); \
            acc[(mh)*4 + i_][(nh)*2 + j_] = __builtin_amdgcn_mfma_f32_16x16x32_bf16( \
                af[i_][1], bfr[j_][1], acc[(mh)*4 + i_][(nh)*2 + j_], 0, 0, 0); } } \
    __builtin_amdgcn_s_setprio(0); } while (0)

    f32x4  acc[8][4] = {};   // [mh*4+i][nh*2+j], AGPR
    bf16x8 af[4][2];         // current m-half A frags
    bf16x8 bfr[2][2];        // current n-half B frags (reloaded per phase)
    f32x4  ar[4];            // A reg-staging (one half-tile)

    // ---- prologue: A(0)->buf0, A(1)->buf1 (reg-staged+cvt), B(0)->buf0.
    {
        f32x4 pr[4];
        GLDA_H(ar, 0, 0); GLDA_H(pr, 0, 128);
        SCHED0;
        STG_B(0, 0, 0); STG_B(0, 0, 64); STG_B(0, 0, 128); STG_B(0, 0, 192);
        asm volatile("s_waitcnt vmcnt(4)" ::: "memory");   // A(0)x8 retired
        SCHED0;
        CVTW_H(ar, 0, 0); CVTW_H(pr, 0, 128);
        GLDA_H(ar, 1, 0); GLDA_H(pr, 1, 128);
        VM0; SCHED0;
        CVTW_H(ar, 1, 0); CVTW_H(pr, 1, 128);
        LGKM0;            // my ds_writes visible before barrier
        BARRIER;
    }

    // Per tile u (buf bb=u&1):
    //  ph1: write A(u+1) half1 -> As[bb^1]; ds-load frags; stage B(u+1) 1/2
    //  ph2: stage B(u+1) 2/2; asm-load A(u+2) half0
    //  ph3: ds-load frags
    //  ph4: drain; cvt+write A(u+2) half0 -> As[bb]; asm-load A(u+2) half1
#define TILE(bb, u_) do { \
    /* ph1 */ \
    if ((u_) >= 1 && (u_) + 1 < NT) { VM0; SCHED0; CVTW_H(ar, (bb) ^ 1, 128); } \
    LOAD_A(bb, 0); LOAD_B(bb, 0); \
    if ((u_) + 1 < NT) { STG_B((bb) ^ 1, (u_) + 1, 0); STG_B((bb) ^ 1, (u_) + 1, 64); } \
    BARRIER; LGKM0; MFMA_Q(0, 0); BARRIER; \
    /* ph2 */ \
    LOAD_B(bb, 1); \
    if ((u_) + 1 < NT) { STG_B((bb) ^ 1, (u_) + 1, 128); STG_B((bb) ^ 1, (u_) + 1, 192); } \
    SCHED0; \
    if ((u_) + 2 < NT) GLDA_H(ar, (u_) + 2, 0); \
    BARRIER; LGKM0; MFMA_Q(0, 1); BARRIER; \
    /* ph3 */ \
    LOAD_A(bb, 1); LOAD_B(bb, 0); \
    BARRIER; LGKM0; MFMA_Q(1, 0); BARRIER; \
    /* ph4 */ \
    LOAD_B(bb, 1); \
    if ((u_) + 2 < NT) { \
        VM0; SCHED0; \
        CVTW_H(ar, bb, 0); \
        GLDA_H(ar, (u_) + 2, 128); \
    } else if ((u_) + 1 < NT) { VM0; } \
    BARRIER; LGKM0; MFMA_Q(1, 1); BARRIER; \
} while (0)

#pragma unroll 1
    for (int u = 0; u < NT; u += 2) {
        TILE(0, u);
        TILE(1, u + 1);
    }

    // ---- epilogue: C = acc + bias
#pragma unroll
    for (int mh = 0; mh < 2; ++mh)
#pragma unroll
        for (int i = 0; i < 4; ++i)
#pragma unroll
            for (int nh = 0; nh < 2; ++nh)
#pragma unroll
                for (int j = 0; j < 2; ++j) {
                    f32x4 v = acc[mh * 4 + i][nh * 2 + j];
                    const int row0 = brow + wr * 128 + mh * 64 + i * 16 + l4 * 4;
                    const int col  = bcol + wc * 64 + nh * 32 + j * 16 + l15;
                    const float bb2 = bias[col];
#pragma unroll
                    for (int r = 0; r < 4; ++r)
                        C[(size_t)(row0 + r) * NDIM + col] = v[r] + bb2;
                }
}

// ---------------- naive fp32 fallback (only if ws too small) ----------------
__global__ __launch_bounds__(256) void gemm_naive(const float* __restrict__ x,
                                                  const float* __restrict__ w,
                                                  const float* __restrict__ bias,
                                                  float* __restrict__ out) {
    long o = (long)blockIdx.x * 256 + threadIdx.x;
    if (o >= (long)MDIM * NDIM) return;
    int b = (int)(o / NDIM), n = (int)(o % NDIM);
    const float* xr = x + (long)b * KDIM;
    const float* wr = w + (long)n * KDIM;
    float s = 0.f;
    for (int k = 0; k < KDIM; ++k) s += xr[k] * wr[k];
    out[o] = s + bias[n];
}

extern "C" void kernel_launch(void* const* d_in, const int* in_sizes, int n_in,
                              void* d_out, int out_size, void* d_ws, size_t ws_size,
                              hipStream_t stream) {
    const float* x    = (const float*)d_in[0];
    const float* w    = (const float*)d_in[1];
    const float* bias = (const float*)d_in[2];
    float* out = (float*)d_out;

    const size_t need = (size_t)NDIM * KDIM * sizeof(ushort);   // 2 MiB (W only)
    if (ws_size >= need) {
        ushort* wb = (ushort*)d_ws;
        const int n8w = NDIM * KDIM / 8;   // 131,072
        cvt_f32_bf16<<<n8w / 256, 256, 0, stream>>>(w, wb, n8w);
        dim3 grid(NDIM / BN, MDIM / BM);   // (4, 64) = 256 blocks
        gemm_8ph<<<grid, 512, 0, stream>>>(x, wb, bias, out);
    } else {
        const long total = (long)MDIM * NDIM;
        gemm_naive<<<(int)((total + 255) / 256), 256, 0, stream>>>(x, w, bias, out);
    }
}

// Round 4
// 59.584 us; speedup vs baseline: 1.3342x; 1.0182x over previous
//
#include <hip/hip_runtime.h>
#include <hip/hip_bf16.h>
#include <stdint.h>

#define MDIM 16384
#define NDIM 1024
#define KDIM 1024
#define BM 256
#define BN 256
#define BK 64
#define NT (KDIM / BK)   // 16 K-tiles

typedef __bf16 bf16x8 __attribute__((ext_vector_type(8)));
typedef float f32x4 __attribute__((ext_vector_type(4)));
typedef uint  u32x4 __attribute__((ext_vector_type(4)));

#define GLOBAL_CPTR(p) ((const __attribute__((address_space(1))) void*)(p))
#define LDS_PTR(p)     ((__attribute__((address_space(3))) void*)(p))

// ---------------- fp32 -> bf16 (RNE) convert (used for W only) --------------
__device__ inline ushort f2bf_rne(float f) {
    union { float f; uint32_t u; } c; c.f = f;
    uint32_t u = c.u;
    return (ushort)((u + 0x7fffu + ((u >> 16) & 1u)) >> 16);
}

__global__ __launch_bounds__(256) void cvt_f32_bf16(const float* __restrict__ src,
                                                    ushort* __restrict__ dst, int n8) {
    int i = blockIdx.x * 256 + threadIdx.x;
    if (i >= n8) return;
    const float4* s4 = (const float4*)src;
    float4 a = s4[2 * i];
    float4 b = s4[2 * i + 1];
    union { ushort us[8]; uint4 u4; } p;
    p.us[0] = f2bf_rne(a.x); p.us[1] = f2bf_rne(a.y);
    p.us[2] = f2bf_rne(a.z); p.us[3] = f2bf_rne(a.w);
    p.us[4] = f2bf_rne(b.x); p.us[5] = f2bf_rne(b.y);
    p.us[6] = f2bf_rne(b.z); p.us[7] = f2bf_rne(b.w);
    ((uint4*)dst)[i] = p.u4;
}

__device__ inline uint pk2bf(float lo, float hi) {
    union { __hip_bfloat162 h2; uint u; } c;
    c.h2 = __float22bfloat162_rn(float2{lo, hi});
    return c.u;
}

// ---------------- fused 256x256 8-phase GEMM ---------------------------------
// C = A(MxK, fp32) * B^T (B = W bf16, NxK) + bias.  A converted fp32->bf16
// in-kernel via reg-staging; ALL main-loop waits are counted (no vmcnt(0)).
// Steady-state invariant at tile-u entry: outstanding VMEM = A(u+1) x8 GLD4.
__global__ __launch_bounds__(512, 2) void gemm_8ph(const float* __restrict__ A,
                                                   const ushort* __restrict__ B,
                                                   const float* __restrict__ bias,
                                                   float* __restrict__ C) {
    __shared__ ushort As[2][BM * BK];   // 2 x 32 KiB
    __shared__ ushort Bs[2][BN * BK];   // 2 x 32 KiB

    const int tid  = threadIdx.x;
    const int lane = tid & 63;
    const int wave = tid >> 6;
    const int wr   = wave >> 2;   // 0..1 : M half
    const int wc   = wave & 3;    // 0..3 : N quarter
    const int l15  = lane & 15;
    const int l4   = lane >> 4;

    // T1: chunked XCD swizzle (bijective, 256 % 8 == 0)
    const int lin  = blockIdx.y * gridDim.x + blockIdx.x;   // 0..255
    const int swz  = (lin & 7) * 32 + (lin >> 3);
    const int brow = (swz >> 2) * BM;
    const int bcol = (swz & 3) * BN;

    const int lrow = tid >> 3;           // 0..63
    const int lcb  = (tid & 7) * 16;     // byte col within row (pre-swizzle)
    const int swb  = (lrow & 7) << 4;
    const int wb0  = lrow * 128 + (lcb ^ swb);   // swizzled ds_write byte off

    // A global source: fp32, LINEAR (swizzle applied at ds_write)
    const float*  Ag   = A + (size_t)(brow + lrow) * KDIM + (tid & 7) * 8;
    // B global source: bf16, inverse-swizzled col (global_load_lds dest linear)
    const ushort* Bsrc = B + (size_t)(bcol + lrow) * KDIM + ((lcb ^ swb) >> 1);

    // fragment ds_read byte offsets (swizzled)
    const int sw   = (l15 & 7) << 4;
    const int off0 = l15 * 128 + ((l4 * 16) ^ sw);
    const int off1 = l15 * 128 + (((l4 * 16) + 64) ^ sw);

#define BARRIER __builtin_amdgcn_s_barrier()
#define LGKM0  asm volatile("s_waitcnt lgkmcnt(0)" ::: "memory")
#define VMC(n) asm volatile("s_waitcnt vmcnt(" #n ")" ::: "memory")
#define SCHED0 __builtin_amdgcn_sched_barrier(0)
#define GLD4(d, p) asm volatile("global_load_dwordx4 %0, %1, off" : "=v"(d) : "v"(p) : "memory")

#define STG_B(bb, t_, r0) __builtin_amdgcn_global_load_lds( \
        GLOBAL_CPTR(Bsrc + (size_t)(r0) * KDIM + (t_) * BK), \
        LDS_PTR(&Bs[bb][(r0) * BK + tid * 8]), 16, 0, 0)

    // issue all 8 A-loads (256 rows x BK) for K-tile t_ into ar[0..7]
#define GLDA_T(t_) do { \
    const float* q_ = Ag + (size_t)(t_) * BK; \
    GLD4(ar[0], q_);                       GLD4(ar[1], q_ + 4); \
    GLD4(ar[2], q_ + (size_t) 64 * KDIM);  GLD4(ar[3], q_ + (size_t) 64 * KDIM + 4); \
    GLD4(ar[4], q_ + (size_t)128 * KDIM);  GLD4(ar[5], q_ + (size_t)128 * KDIM + 4); \
    GLD4(ar[6], q_ + (size_t)192 * KDIM);  GLD4(ar[7], q_ + (size_t)192 * KDIM + 4); } while (0)

    // convert ar[0..7] and ds_write (swizzled) the full 256-row A tile
#define CVTW_T(bb) do { _Pragma("unroll") \
    for (int h_ = 0; h_ < 4; ++h_) { \
        u32x4 k_; \
        k_.x = pk2bf(ar[2*h_].x, ar[2*h_].y); k_.y = pk2bf(ar[2*h_].z, ar[2*h_].w); \
        k_.z = pk2bf(ar[2*h_+1].x, ar[2*h_+1].y); k_.w = pk2bf(ar[2*h_+1].z, ar[2*h_+1].w); \
        *(u32x4*)((char*)&As[bb][0] + h_ * 64 * 128 + wb0) = k_; } } while (0)

#define LOAD_A(bb, mh) do { _Pragma("unroll") \
    for (int i_ = 0; i_ < 4; ++i_) { \
        const char* pb_ = (const char*)&As[bb][0] + (wr * 128 + (mh) * 64 + i_ * 16) * 128; \
        af[i_][0] = *(const bf16x8*)(pb_ + off0); \
        af[i_][1] = *(const bf16x8*)(pb_ + off1); } } while (0)

#define LOAD_B(bb, nh) do { _Pragma("unroll") \
    for (int j_ = 0; j_ < 2; ++j_) { \
        const char* pb_ = (const char*)&Bs[bb][0] + (wc * 64 + (nh) * 32 + j_ * 16) * 128; \
        bfr[j_][0] = *(const bf16x8*)(pb_ + off0); \
        bfr[j_][1] = *(const bf16x8*)(pb_ + off1); } } while (0)

#define MFMA_Q(mh, nh) do { __builtin_amdgcn_s_setprio(1); _Pragma("unroll") \
    for (int i_ = 0; i_ < 4; ++i_) { _Pragma("unroll") \
        for (int j_ = 0; j_ < 2; ++j_) { \
            acc[(mh)*4 + i_][(nh)*2 + j_] = __builtin_amdgcn_mfma_f32_16x16x32_bf16( \
                af[i_][0], bfr[j_][0], acc[(mh)*4 + i_][(nh)*2 + j_], 0, 0, 0); \
            acc[(mh)*4 + i_][(nh)*2 + j_] = __builtin_amdgcn_mfma_f32_16x16x32_bf16( \
                af[i_][1], bfr[j_][1], acc[(mh)*4 + i_][(nh)*2 + j_], 0, 0, 0); } } \
    __builtin_amdgcn_s_setprio(0); } while (0)

    f32x4  acc[8][4] = {};   // [mh*4+i][nh*2+j] (AGPR side)
    bf16x8 af[4][2];         // current m-half A frags
    bf16x8 bfr[2][2];        // current n-half B frags (reloaded per phase)
    f32x4  ar[8];            // A reg-staging, full 256-row K-tile

    // ---- prologue (counted): A(0), B(0), then A(1) in flight at loop entry.
    GLDA_T(0);                                          // A0 x8
    STG_B(0, 0, 0); STG_B(0, 0, 64);
    STG_B(0, 0, 128); STG_B(0, 0, 192);                 // +B0 x4 = 12
    VMC(4); SCHED0;                                     // A0 retired (B0 in flight)
    CVTW_T(0);
    SCHED0;
    GLDA_T(1);                                          // +A1 x8
    VMC(8); SCHED0;                                     // B0 retired (A1 in flight)
    LGKM0;                                              // my ds_writes visible
    BARRIER;

    // Per tile u (buf bb = u&1):
    //  ph1: stage B(u+1) 1/2 -> Bs[bb^1]
    //  ph2: stage B(u+1) 2/2
    //  ph3: vmcnt(4) [retire A(u+1), B stays]; cvt+write A(u+1)->As[bb^1];
    //       issue A(u+2) x8
    //  ph4: vmcnt(8) [retire B(u+1), A(u+2) stays]
#define TILE(bb, u_) do { \
    /* ph1 */ \
    LOAD_A(bb, 0); LOAD_B(bb, 0); \
    if ((u_) + 1 < NT) { STG_B((bb) ^ 1, (u_) + 1, 0); STG_B((bb) ^ 1, (u_) + 1, 64); } \
    BARRIER; LGKM0; SCHED0; MFMA_Q(0, 0); BARRIER; \
    /* ph2 */ \
    LOAD_B(bb, 1); \
    if ((u_) + 1 < NT) { STG_B((bb) ^ 1, (u_) + 1, 128); STG_B((bb) ^ 1, (u_) + 1, 192); } \
    BARRIER; LGKM0; SCHED0; MFMA_Q(0, 1); BARRIER; \
    /* ph3 */ \
    if ((u_) + 1 < NT) { VMC(4); SCHED0; CVTW_T((bb) ^ 1); SCHED0; } \
    if ((u_) + 2 < NT) { GLDA_T((u_) + 2); SCHED0; } \
    LOAD_A(bb, 1); LOAD_B(bb, 0); \
    BARRIER; LGKM0; SCHED0; MFMA_Q(1, 0); BARRIER; \
    /* ph4 */ \
    LOAD_B(bb, 1); \
    if ((u_) + 2 < NT)      { VMC(8); } \
    else if ((u_) + 1 < NT) { VMC(0); } \
    BARRIER; LGKM0; SCHED0; MFMA_Q(1, 1); BARRIER; \
} while (0)

#pragma unroll 1
    for (int u = 0; u < NT; u += 2) {
        TILE(0, u);
        TILE(1, u + 1);
    }

    // ---- epilogue: C = acc + bias
#pragma unroll
    for (int mh = 0; mh < 2; ++mh)
#pragma unroll
        for (int i = 0; i < 4; ++i)
#pragma unroll
            for (int nh = 0; nh < 2; ++nh)
#pragma unroll
                for (int j = 0; j < 2; ++j) {
                    f32x4 v = acc[mh * 4 + i][nh * 2 + j];
                    const int row0 = brow + wr * 128 + mh * 64 + i * 16 + l4 * 4;
                    const int col  = bcol + wc * 64 + nh * 32 + j * 16 + l15;
                    const float bb2 = bias[col];
#pragma unroll
                    for (int r = 0; r < 4; ++r)
                        C[(size_t)(row0 + r) * NDIM + col] = v[r] + bb2;
                }
}

// ---------------- naive fp32 fallback (only if ws too small) ----------------
__global__ __launch_bounds__(256) void gemm_naive(const float* __restrict__ x,
                                                  const float* __restrict__ w,
                                                  const float* __restrict__ bias,
                                                  float* __restrict__ out) {
    long o = (long)blockIdx.x * 256 + threadIdx.x;
    if (o >= (long)MDIM * NDIM) return;
    int b = (int)(o / NDIM), n = (int)(o % NDIM);
    const float* xr = x + (long)b * KDIM;
    const float* wr = w + (long)n * KDIM;
    float s = 0.f;
    for (int k = 0; k < KDIM; ++k) s += xr[k] * wr[k];
    out[o] = s + bias[n];
}

extern "C" void kernel_launch(void* const* d_in, const int* in_sizes, int n_in,
                              void* d_out, int out_size, void* d_ws, size_t ws_size,
                              hipStream_t stream) {
    const float* x    = (const float*)d_in[0];
    const float* w    = (const float*)d_in[1];
    const float* bias = (const float*)d_in[2];
    float* out = (float*)d_out;

    const size_t need = (size_t)NDIM * KDIM * sizeof(ushort);   // 2 MiB (W only)
    if (ws_size >= need) {
        ushort* wb = (ushort*)d_ws;
        const int n8w = NDIM * KDIM / 8;   // 131,072
        cvt_f32_bf16<<<n8w / 256, 256, 0, stream>>>(w, wb, n8w);
        dim3 grid(NDIM / BN, MDIM / BM);   // (4, 64) = 256 blocks
        gemm_8ph<<<grid, 512, 0, stream>>>(x, wb, bias, out);
    } else {
        const long total = (long)MDIM * NDIM;
        gemm_naive<<<(int)((total + 255) / 256), 256, 0, stream>>>(x, w, bias, out);
    }
}